// Round 6
// baseline (271.371 us; speedup 1.0000x reference)
//
#include <hip/hip_runtime.h>
#include <stdint.h>

typedef __attribute__((ext_vector_type(4))) float f32x4;
typedef __attribute__((ext_vector_type(8))) short bf16x8;
typedef __attribute__((ext_vector_type(4))) unsigned short u16x4;

#define MFMA16(a, b, c) __builtin_amdgcn_mfma_f32_16x16x32_bf16((a), (b), (c), 0, 0, 0)

static __device__ __forceinline__ unsigned short f2bf(float x) {
  union { float f; unsigned int u; } v; v.f = x;
  unsigned int r = v.u + 0x7fffu + ((v.u >> 16) & 1u);   // RNE
  return (unsigned short)(r >> 16);
}

static __device__ __forceinline__ void gload_lds16(const void* g, void* l) {
  __builtin_amdgcn_global_load_lds(
      (__attribute__((address_space(1))) void*)(g),
      (__attribute__((address_space(3))) void*)(l), 16, 0, 0);
}

// ---------------- weight convert + transpose: Wt[n][k] = bf16(W[k][n]) ----------------
__global__ __launch_bounds__(256) void wtrans_kernel(
    const float* __restrict__ W0, const float* __restrict__ W1, const float* __restrict__ W2,
    unsigned short* __restrict__ T0, unsigned short* __restrict__ T1, unsigned short* __restrict__ T2)
{
  __shared__ __align__(16) float tile[64][65];
  const float* W = (blockIdx.z == 0) ? W0 : (blockIdx.z == 1) ? W1 : W2;
  unsigned short* T = (blockIdx.z == 0) ? T0 : (blockIdx.z == 1) ? T1 : T2;
  const int t = threadIdx.x;
  const int kb = blockIdx.x * 64, nb = blockIdx.y * 64;
  const int rr = t >> 4, cc = (t & 15) * 4;
#pragma unroll
  for (int p = 0; p < 4; ++p) {
    const int r = rr + p * 16;
    const f32x4 v = *(const f32x4*)&W[(size_t)(kb + r) * 1024 + nb + cc];
#pragma unroll
    for (int j = 0; j < 4; ++j) tile[r][cc + j] = v[j];
  }
  __syncthreads();
#pragma unroll
  for (int p = 0; p < 4; ++p) {
    const int n = rr + p * 16;
    u16x4 o;
#pragma unroll
    for (int j = 0; j < 4; ++j) o[j] = f2bf(tile[cc + j][n]);
    *(u16x4*)&T[(size_t)(nb + n) * 1024 + kb + cc] = o;
  }
}

// ---------------- merged projection GEMM (z selects Q/K/V) ----------------
// C[m][n] = sum_k A[m][k] * Wt[n][k];  A: f32 [8192][1024], Wt: bf16 [1024][1024].
// z=0: qa (scaled 1/8, [bh][s][d]); z=1: ka ([bh][s][d]); z=2: va transposed ([bh][d][s]).
__global__ __launch_bounds__(256) void proj_gemm_kernel(
    const float* __restrict__ A0, const float* __restrict__ A1, const float* __restrict__ A2,
    const unsigned short* __restrict__ B0, const unsigned short* __restrict__ B1,
    const unsigned short* __restrict__ B2,
    unsigned short* __restrict__ O0, unsigned short* __restrict__ O1,
    unsigned short* __restrict__ O2)
{
  const int z = blockIdx.z;
  const float* A = (z == 0) ? A0 : (z == 1) ? A1 : A2;
  const unsigned short* Bt = (z == 0) ? B0 : (z == 1) ? B1 : B2;
  unsigned short* outp = (z == 0) ? O0 : (z == 1) ? O1 : O2;
  const float scale = (z == 0) ? 0.125f : 1.0f;

  __shared__ __align__(16) unsigned short Alds[128 * 32];
  __shared__ __align__(16) unsigned short Blds[128 * 32];
  const int t = threadIdx.x;
  const int lane = t & 63, w = t >> 6;
  const int wr = w >> 1, wc = w & 1;
  const int m0 = blockIdx.y * 128, n0 = blockIdx.x * 128;

  f32x4 acc[4][4] = {};
  const int ar = t >> 1, ac = (t & 1) * 16;
  const float* aptr = A + (size_t)(m0 + ar) * 1024 + ac;

  for (int kt = 0; kt < 1024; kt += 32) {
    const f32x4 a0 = *(const f32x4*)(aptr + kt);
    const f32x4 a1 = *(const f32x4*)(aptr + kt + 4);
    const f32x4 a2 = *(const f32x4*)(aptr + kt + 8);
    const f32x4 a3 = *(const f32x4*)(aptr + kt + 12);
    bf16x8 p0, p1;
#pragma unroll
    for (int u = 0; u < 4; ++u) {
      p0[u]     = (short)f2bf(a0[u]);
      p0[u + 4] = (short)f2bf(a1[u]);
      p1[u]     = (short)f2bf(a2[u]);
      p1[u + 4] = (short)f2bf(a3[u]);
    }
    *(bf16x8*)&Alds[ar * 32 + ac]     = p0;
    *(bf16x8*)&Alds[ar * 32 + ac + 8] = p1;
#pragma unroll
    for (int i = 0; i < 2; ++i) {
      const int e = (t + i * 256) * 8;
      const int n = e >> 5, kk = e & 31;
      gload_lds16(&Bt[(size_t)(n0 + n) * 1024 + kt + kk], &Blds[e]);
    }
    __syncthreads();

    bf16x8 af[4], bfv[4];
#pragma unroll
    for (int m = 0; m < 4; ++m)
      af[m] = *(const bf16x8*)&Alds[(wr * 64 + m * 16 + (lane & 15)) * 32 + (lane >> 4) * 8];
#pragma unroll
    for (int n = 0; n < 4; ++n)
      bfv[n] = *(const bf16x8*)&Blds[(wc * 64 + n * 16 + (lane & 15)) * 32 + (lane >> 4) * 8];
#pragma unroll
    for (int m = 0; m < 4; ++m)
#pragma unroll
      for (int n = 0; n < 4; ++n)
        acc[m][n] = MFMA16(af[m], bfv[n], acc[m][n]);
    __syncthreads();
  }

  // epilogue: C/D layout col=lane&15, row=(lane>>4)*4+reg  [m89]
#pragma unroll
  for (int mi = 0; mi < 4; ++mi) {
#pragma unroll
    for (int ni = 0; ni < 4; ++ni) {
      const int nn = n0 + wc * 64 + ni * 16 + (lane & 15);
      const int h = nn >> 6, d = nn & 63;
      const int mbase = m0 + wr * 64 + mi * 16 + ((lane >> 4) << 2);
      const int b = mbase >> 11;
      const int s = mbase & 2047;
      if (z != 2) {
#pragma unroll
        for (int j = 0; j < 4; ++j)
          outp[((size_t)(b * 16 + h) * 2048 + (s + j)) * 64 + d] = f2bf(acc[mi][ni][j] * scale);
      } else {
        u16x4 o;
#pragma unroll
        for (int j = 0; j < 4; ++j) o[j] = f2bf(acc[mi][ni][j]);
        *(u16x4*)&outp[((size_t)(b * 16 + h) * 64 + d) * 2048 + s] = o;
      }
    }
  }
}

// ---------------- flash attention (LDS-free K/V: direct global B-fragments) ----------
// qa/ka: bf16 [BH][2048][64] (q pre-scaled by 1/8). va: bf16 [BH][64][2048].
// out: f32 [B][2048][1024]. One block = one (b,h) x 64 q-rows; 4 waves x 16 rows.
// No __syncthreads in the K-loop: K/V fragments load straight from global (L2-resident),
// P round-trips through a per-wave-private LDS buffer (wave-internal ordering only).
__global__ __launch_bounds__(256) void attn_kernel(
    const unsigned short* __restrict__ qa, const unsigned short* __restrict__ ka,
    const unsigned short* __restrict__ va, const int* __restrict__ Qlen,
    const int* __restrict__ Vlen, float* __restrict__ outp)
{
  __shared__ __align__(16) unsigned short Plds[4][16 * 64];
  const int t = threadIdx.x, lane = t & 63, w = t >> 6;
  const int bh = blockIdx.y, b = bh >> 4, h = bh & 15;
  const int q0 = blockIdx.x * 64;
  const int Lq = Qlen[b], Lv = Vlen[b];
  float* outb = outp + (size_t)b * 2048 * 1024 + h * 64;

  if (q0 >= Lq) {  // entire q-tile masked: zero our 64x64 f32 slab
    const int r = t >> 2, c0 = (t & 3) * 16;
    const f32x4 z = {0.f, 0.f, 0.f, 0.f};
#pragma unroll
    for (int j = 0; j < 4; ++j)
      *(f32x4*)&outb[(size_t)(q0 + r) * 1024 + c0 + j * 4] = z;
    return;
  }

  const unsigned short* qb = qa + (size_t)bh * 2048 * 64;
  const unsigned short* kb = ka + (size_t)bh * 2048 * 64;
  const unsigned short* vb = va + (size_t)bh * 64 * 2048;

  // Q A-fragments in registers (row = lane&15, k = (lane>>4)*8, 2 halves of Dh=64)
  bf16x8 aq[2];
  {
    const int qrow = q0 + w * 16 + (lane & 15);
#pragma unroll
    for (int f = 0; f < 2; ++f)
      aq[f] = *(const bf16x8*)&qb[(size_t)qrow * 64 + (lane >> 4) * 8 + f * 32];
  }

  float m_run[4], l_run[4];
  f32x4 acc_o[4] = {};
#pragma unroll
  for (int j = 0; j < 4; ++j) { m_run[j] = -3.0e38f; l_run[j] = 0.0f; }

  const int nt = (Lv + 63) >> 6;
  for (int kt = 0; kt < nt; ++kt) {
    const int k0 = kt * 64;

    // QK^T: B-fragments directly from global (row = kpos, k-contiguous)
    f32x4 s4[4];
#pragma unroll
    for (int kbk = 0; kbk < 4; ++kbk) {
      const int row = kbk * 16 + (lane & 15);
      f32x4 acc = {0.f, 0.f, 0.f, 0.f};
#pragma unroll
      for (int ds = 0; ds < 2; ++ds) {
        const int col = (lane >> 4) * 8 + ds * 32;
        const bf16x8 bk = *(const bf16x8*)&kb[(size_t)(k0 + row) * 64 + col];
        acc = MFMA16(aq[ds], bk, acc);
      }
      if (k0 + row >= Lv) {   // V_len mask (output col = lane&15-indexed kpos)
#pragma unroll
        for (int j = 0; j < 4; ++j) acc[j] = -1e30f;
      }
      s4[kbk] = acc;
    }

    // online softmax: rowmax over 4 blocks + 16-lane butterfly (reduce over cols)
    f32x4 rm;
#pragma unroll
    for (int j = 0; j < 4; ++j)
      rm[j] = fmaxf(fmaxf(s4[0][j], s4[1][j]), fmaxf(s4[2][j], s4[3][j]));
#pragma unroll
    for (int msk = 1; msk <= 8; msk <<= 1)
#pragma unroll
      for (int j = 0; j < 4; ++j)
        rm[j] = fmaxf(rm[j], __shfl_xor(rm[j], msk));

    float mn[4], esc[4];
#pragma unroll
    for (int j = 0; j < 4; ++j) {
      mn[j] = fmaxf(m_run[j], rm[j]);
      esc[j] = __expf(m_run[j] - mn[j]);
      m_run[j] = mn[j];
    }

    float p[4][4];
    f32x4 rs = {0.f, 0.f, 0.f, 0.f};
#pragma unroll
    for (int kbk = 0; kbk < 4; ++kbk)
#pragma unroll
      for (int j = 0; j < 4; ++j) {
        p[kbk][j] = __expf(s4[kbk][j] - mn[j]);
        rs[j] += p[kbk][j];
      }
#pragma unroll
    for (int msk = 1; msk <= 8; msk <<= 1)
#pragma unroll
      for (int j = 0; j < 4; ++j)
        rs[j] += __shfl_xor(rs[j], msk);
#pragma unroll
    for (int j = 0; j < 4; ++j) l_run[j] = l_run[j] * esc[j] + rs[j];
#pragma unroll
    for (int d = 0; d < 4; ++d)
#pragma unroll
      for (int j = 0; j < 4; ++j) acc_o[d][j] *= esc[j];

    // P (C-layout) -> per-wave LDS (swizzled) -> A-fragments; no barrier needed
    unsigned short* pl = &Plds[w][0];
#pragma unroll
    for (int kbk = 0; kbk < 4; ++kbk)
#pragma unroll
      for (int j = 0; j < 4; ++j) {
        const int row = (lane >> 4) * 4 + j;
        const int col = (kbk * 16 + (lane & 15)) ^ ((row & 7) << 3);
        pl[row * 64 + col] = f2bf(p[kbk][j]);
      }
    bf16x8 pf[2];
#pragma unroll
    for (int ks = 0; ks < 2; ++ks) {
      const int row = lane & 15;
      const int col = ((lane >> 4) * 8 + ks * 32) ^ ((row & 7) << 3);
      pf[ks] = *(const bf16x8*)&pl[row * 64 + col];
    }

    // PV: V B-fragments directly from global (v_t layout: row = d, k-contiguous)
#pragma unroll
    for (int db = 0; db < 4; ++db) {
#pragma unroll
      for (int ks = 0; ks < 2; ++ks) {
        const int vrow = db * 16 + (lane & 15);
        const int vcol = (lane >> 4) * 8 + ks * 32;
        const bf16x8 vf = *(const bf16x8*)&vb[(size_t)vrow * 2048 + k0 + vcol];
        acc_o[db] = MFMA16(pf[ks], vf, acc_o[db]);
      }
    }
  }

  // epilogue: normalize, Q_len mask, write f32
#pragma unroll
  for (int j = 0; j < 4; ++j) {
    const int row = q0 + w * 16 + (lane >> 4) * 4 + j;
    const float rl = 1.0f / l_run[j];
#pragma unroll
    for (int db = 0; db < 4; ++db) {
      const float v = acc_o[db][j] * rl;
      outb[(size_t)row * 1024 + db * 16 + (lane & 15)] = (row < Lq) ? v : 0.0f;
    }
  }
}

extern "C" void kernel_launch(void* const* d_in, const int* in_sizes, int n_in,
                              void* d_out, int out_size, void* d_ws, size_t ws_size,
                              hipStream_t stream) {
  float* out = (float*)d_out;

  const float* Qs = (const float*)d_in[0];
  const float* Ks = (const float*)d_in[1];
  const float* Vs = (const float*)d_in[2];
  const float* WQ = (const float*)d_in[3];
  const float* WK = (const float*)d_in[4];
  const float* WV = (const float*)d_in[5];
  const int* Qlen = (const int*)d_in[6];
  const int* Vlen = (const int*)d_in[7];

  unsigned short* WQt = (unsigned short*)d_ws;
  unsigned short* WKt = WQt + (size_t)1024 * 1024;
  unsigned short* WVt = WKt + (size_t)1024 * 1024;
  unsigned short* qa  = WVt + (size_t)1024 * 1024;
  unsigned short* ka  = qa + (size_t)8192 * 1024;
  unsigned short* va  = ka + (size_t)8192 * 1024;

  wtrans_kernel<<<dim3(16, 16, 3), 256, 0, stream>>>(WQ, WK, WV, WQt, WKt, WVt);
  proj_gemm_kernel<<<dim3(8, 64, 3), 256, 0, stream>>>(
      Qs, Ks, Vs, WQt, WKt, WVt, qa, ka, va);
  attn_kernel<<<dim3(32, 64), 256, 0, stream>>>(qa, ka, va, Qlen, Vlen, out);
}

// Round 7
// 187.021 us; speedup vs baseline: 1.4510x; 1.4510x over previous
//
#include <hip/hip_runtime.h>
#include <stdint.h>

typedef __attribute__((ext_vector_type(4))) float f32x4;
typedef __attribute__((ext_vector_type(8))) short bf16x8;
typedef __attribute__((ext_vector_type(4))) unsigned short u16x4;

#define MFMA16(a, b, c) __builtin_amdgcn_mfma_f32_16x16x32_bf16((a), (b), (c), 0, 0, 0)

static __device__ __forceinline__ unsigned short f2bf(float x) {
  union { float f; unsigned int u; } v; v.f = x;
  unsigned int r = v.u + 0x7fffu + ((v.u >> 16) & 1u);   // RNE
  return (unsigned short)(r >> 16);
}

static __device__ __forceinline__ void gload_lds16(const void* g, void* l) {
  __builtin_amdgcn_global_load_lds(
      (__attribute__((address_space(1))) void*)(g),
      (__attribute__((address_space(3))) void*)(l), 16, 0, 0);
}

// ---------------- weight convert + transpose: Wt[n][k] = bf16(W[k][n]) ----------------
__global__ __launch_bounds__(256) void wtrans_kernel(
    const float* __restrict__ W0, const float* __restrict__ W1, const float* __restrict__ W2,
    unsigned short* __restrict__ T0, unsigned short* __restrict__ T1, unsigned short* __restrict__ T2)
{
  __shared__ __align__(16) float tile[64][65];
  const float* W = (blockIdx.z == 0) ? W0 : (blockIdx.z == 1) ? W1 : W2;
  unsigned short* T = (blockIdx.z == 0) ? T0 : (blockIdx.z == 1) ? T1 : T2;
  const int t = threadIdx.x;
  const int kb = blockIdx.x * 64, nb = blockIdx.y * 64;
  const int rr = t >> 4, cc = (t & 15) * 4;
#pragma unroll
  for (int p = 0; p < 4; ++p) {
    const int r = rr + p * 16;
    const f32x4 v = *(const f32x4*)&W[(size_t)(kb + r) * 1024 + nb + cc];
#pragma unroll
    for (int j = 0; j < 4; ++j) tile[r][cc + j] = v[j];
  }
  __syncthreads();
#pragma unroll
  for (int p = 0; p < 4; ++p) {
    const int n = rr + p * 16;
    u16x4 o;
#pragma unroll
    for (int j = 0; j < 4; ++j) o[j] = f2bf(tile[cc + j][n]);
    *(u16x4*)&T[(size_t)(nb + n) * 1024 + kb + cc] = o;
  }
}

// ---------------- merged projection GEMM (z selects Q/K/V) ----------------
// C[m][n] = sum_k A[m][k] * Wt[n][k];  A: f32 [8192][1024], Wt: bf16 [1024][1024].
// Grid (x=m-tile 64, y=n-tile 8, z=3): bid%8 = x%8 -> all n-tiles of one A-panel
// share an XCD L2 (A fetched ~once). LDS chunk-XOR swizzle: 16B chunk c stored at
// c ^ ((row>>1)&3) -> fragment reads cover all 8 granule groups 2-way (conflict-free).
__global__ __launch_bounds__(256) void proj_gemm_kernel(
    const float* __restrict__ A0, const float* __restrict__ A1, const float* __restrict__ A2,
    const unsigned short* __restrict__ B0, const unsigned short* __restrict__ B1,
    const unsigned short* __restrict__ B2,
    unsigned short* __restrict__ O0, unsigned short* __restrict__ O1,
    unsigned short* __restrict__ O2)
{
  const int z = blockIdx.z;
  const float* A = (z == 0) ? A0 : (z == 1) ? A1 : A2;
  const unsigned short* Bt = (z == 0) ? B0 : (z == 1) ? B1 : B2;
  unsigned short* outp = (z == 0) ? O0 : (z == 1) ? O1 : O2;
  const float scale = (z == 0) ? 0.125f : 1.0f;

  __shared__ __align__(16) unsigned short Alds[128 * 32];
  __shared__ __align__(16) unsigned short Blds[128 * 32];
  const int t = threadIdx.x;
  const int lane = t & 63, w = t >> 6;
  const int wr = w >> 1, wc = w & 1;
  const int m0 = blockIdx.x * 128, n0 = blockIdx.y * 128;

  f32x4 acc[4][4] = {};
  const int ar = t >> 1;                  // A-stage row 0..127
  const int acb = (t & 1) * 2;            // A-stage base chunk (0 or 2); chunk = 8 bf16
  const int asw = (ar >> 1) & 3;          // swizzle for this row
  const float* aptr = A + (size_t)(m0 + ar) * 1024 + acb * 8;

  for (int kt = 0; kt < 1024; kt += 32) {
    // stage A: 16 f32 -> 16 bf16 -> 2x ds_write_b128 at swizzled chunk positions
    const f32x4 a0 = *(const f32x4*)(aptr + kt);
    const f32x4 a1 = *(const f32x4*)(aptr + kt + 4);
    const f32x4 a2 = *(const f32x4*)(aptr + kt + 8);
    const f32x4 a3 = *(const f32x4*)(aptr + kt + 12);
    bf16x8 p0, p1;
#pragma unroll
    for (int u = 0; u < 4; ++u) {
      p0[u]     = (short)f2bf(a0[u]);
      p0[u + 4] = (short)f2bf(a1[u]);
      p1[u]     = (short)f2bf(a2[u]);
      p1[u + 4] = (short)f2bf(a3[u]);
    }
    *(bf16x8*)&Alds[ar * 32 + ((acb ^ asw) * 8)]       = p0;
    *(bf16x8*)&Alds[ar * 32 + (((acb + 1) ^ asw) * 8)] = p1;
    // stage B: gload_lds linear dest, pre-swizzled global source (rule 21)
#pragma unroll
    for (int i = 0; i < 2; ++i) {
      const int L = t + i * 256;           // linear chunk index 0..511
      const int r = L >> 2, cs = L & 3;
      const int c = cs ^ ((r >> 1) & 3);
      gload_lds16(&Bt[(size_t)(n0 + r) * 1024 + kt + c * 8], &Blds[L * 8]);
    }
    __syncthreads();

    bf16x8 af[4], bfv[4];
    const int q = lane >> 4;
#pragma unroll
    for (int m = 0; m < 4; ++m) {
      const int row = wr * 64 + m * 16 + (lane & 15);
      af[m] = *(const bf16x8*)&Alds[row * 32 + ((q ^ ((row >> 1) & 3)) * 8)];
    }
#pragma unroll
    for (int n = 0; n < 4; ++n) {
      const int row = wc * 64 + n * 16 + (lane & 15);
      bfv[n] = *(const bf16x8*)&Blds[row * 32 + ((q ^ ((row >> 1) & 3)) * 8)];
    }
#pragma unroll
    for (int m = 0; m < 4; ++m)
#pragma unroll
      for (int n = 0; n < 4; ++n)
        acc[m][n] = MFMA16(af[m], bfv[n], acc[m][n]);
    __syncthreads();
  }

  // epilogue: C/D layout col=lane&15, row=(lane>>4)*4+reg  [m89]
#pragma unroll
  for (int mi = 0; mi < 4; ++mi) {
#pragma unroll
    for (int ni = 0; ni < 4; ++ni) {
      const int nn = n0 + wc * 64 + ni * 16 + (lane & 15);
      const int h = nn >> 6, d = nn & 63;
      const int mbase = m0 + wr * 64 + mi * 16 + ((lane >> 4) << 2);
      const int b = mbase >> 11;
      const int s = mbase & 2047;
      if (z != 2) {
#pragma unroll
        for (int j = 0; j < 4; ++j)
          outp[((size_t)(b * 16 + h) * 2048 + (s + j)) * 64 + d] = f2bf(acc[mi][ni][j] * scale);
      } else {
        u16x4 o;
#pragma unroll
        for (int j = 0; j < 4; ++j) o[j] = f2bf(acc[mi][ni][j]);
        *(u16x4*)&outp[((size_t)(b * 16 + h) * 64 + d) * 2048 + s] = o;
      }
    }
  }
}

// ---------------- flash attention (round-5 known-good: LDS-staged K/V) ----------
// qa/ka: bf16 [BH][2048][64] (q pre-scaled by 1/8). va: bf16 [BH][64][2048].
// out: f32 [B][2048][1024]. One block = one (b,h) x 64 q-rows; 4 waves x 16 rows.
__global__ __launch_bounds__(256) void attn_kernel(
    const unsigned short* __restrict__ qa, const unsigned short* __restrict__ ka,
    const unsigned short* __restrict__ va, const int* __restrict__ Qlen,
    const int* __restrict__ Vlen, float* __restrict__ outp)
{
  __shared__ __align__(16) unsigned short Klds[64 * 64];   // [kpos][d], XOR-swizzled
  __shared__ __align__(16) unsigned short Vlds[64 * 64];   // [d][kpos], XOR-swizzled
  __shared__ __align__(16) unsigned short Plds[4][16 * 64];
  const int t = threadIdx.x, lane = t & 63, w = t >> 6;
  const int bh = blockIdx.y, b = bh >> 4, h = bh & 15;
  const int q0 = blockIdx.x * 64;
  const int Lq = Qlen[b], Lv = Vlen[b];
  float* outb = outp + (size_t)b * 2048 * 1024 + h * 64;

  if (q0 >= Lq) {  // entire q-tile masked: zero our 64x64 f32 slab
    const int r = t >> 2, c0 = (t & 3) * 16;
    const f32x4 z = {0.f, 0.f, 0.f, 0.f};
#pragma unroll
    for (int j = 0; j < 4; ++j)
      *(f32x4*)&outb[(size_t)(q0 + r) * 1024 + c0 + j * 4] = z;
    return;
  }

  const unsigned short* qb = qa + (size_t)bh * 2048 * 64;
  const unsigned short* kb = ka + (size_t)bh * 2048 * 64;
  const unsigned short* vb = va + (size_t)bh * 64 * 2048;

  bf16x8 aq[2];
  {
    const int qrow = q0 + w * 16 + (lane & 15);
#pragma unroll
    for (int f = 0; f < 2; ++f)
      aq[f] = *(const bf16x8*)&qb[(size_t)qrow * 64 + (lane >> 4) * 8 + f * 32];
  }

  float m_run[4], l_run[4];
  f32x4 acc_o[4] = {};
#pragma unroll
  for (int j = 0; j < 4; ++j) { m_run[j] = -3.0e38f; l_run[j] = 0.0f; }

  const int nt = (Lv + 63) >> 6;
  for (int kt = 0; kt < nt; ++kt) {
    const int k0 = kt * 64;
    // reg-staged K/V with software XOR swizzle: Klds[r][x] = K[k0+r][x ^ ((r&7)*8)]
#pragma unroll
    for (int i = 0; i < 2; ++i) {
      const int cidx = t + i * 256;          // 512 chunks of 8 elements
      const int r = cidx >> 3, c8 = cidx & 7;
      const int dst = r * 64 + ((c8 ^ (r & 7)) * 8);
      const bf16x8 kv = *(const bf16x8*)&kb[(size_t)(k0 + r) * 64 + c8 * 8];
      const bf16x8 vv = *(const bf16x8*)&vb[(size_t)r * 2048 + k0 + c8 * 8];
      *(bf16x8*)&Klds[dst] = kv;
      *(bf16x8*)&Vlds[dst] = vv;
    }
    __syncthreads();

    // QK^T: S-tile 16q x 64k per wave; B-frag rows = kpos, swizzled read
    f32x4 s4[4];
#pragma unroll
    for (int kbk = 0; kbk < 4; ++kbk) {
      const int row = kbk * 16 + (lane & 15);
      f32x4 acc = {0.f, 0.f, 0.f, 0.f};
#pragma unroll
      for (int ds = 0; ds < 2; ++ds) {
        const int col = (((lane >> 4) * 8) + ds * 32) ^ ((row & 7) << 3);
        const bf16x8 bk = *(const bf16x8*)&Klds[row * 64 + col];
        acc = MFMA16(aq[ds], bk, acc);
      }
      if (k0 + row >= Lv) {
#pragma unroll
        for (int j = 0; j < 4; ++j) acc[j] = -1e30f;
      }
      s4[kbk] = acc;
    }

    // online softmax
    f32x4 rm;
#pragma unroll
    for (int j = 0; j < 4; ++j)
      rm[j] = fmaxf(fmaxf(s4[0][j], s4[1][j]), fmaxf(s4[2][j], s4[3][j]));
#pragma unroll
    for (int msk = 1; msk <= 8; msk <<= 1)
#pragma unroll
      for (int j = 0; j < 4; ++j)
        rm[j] = fmaxf(rm[j], __shfl_xor(rm[j], msk));

    float mn[4], esc[4];
#pragma unroll
    for (int j = 0; j < 4; ++j) {
      mn[j] = fmaxf(m_run[j], rm[j]);
      esc[j] = __expf(m_run[j] - mn[j]);
      m_run[j] = mn[j];
    }

    float p[4][4];
    f32x4 rs = {0.f, 0.f, 0.f, 0.f};
#pragma unroll
    for (int kbk = 0; kbk < 4; ++kbk)
#pragma unroll
      for (int j = 0; j < 4; ++j) {
        p[kbk][j] = __expf(s4[kbk][j] - mn[j]);
        rs[j] += p[kbk][j];
      }
#pragma unroll
    for (int msk = 1; msk <= 8; msk <<= 1)
#pragma unroll
      for (int j = 0; j < 4; ++j)
        rs[j] += __shfl_xor(rs[j], msk);
#pragma unroll
    for (int j = 0; j < 4; ++j) l_run[j] = l_run[j] * esc[j] + rs[j];
#pragma unroll
    for (int d = 0; d < 4; ++d)
#pragma unroll
      for (int j = 0; j < 4; ++j) acc_o[d][j] *= esc[j];

    // P (C-layout) -> per-wave LDS (swizzled) -> A-fragments
    unsigned short* pl = &Plds[w][0];
#pragma unroll
    for (int kbk = 0; kbk < 4; ++kbk)
#pragma unroll
      for (int j = 0; j < 4; ++j) {
        const int row = (lane >> 4) * 4 + j;
        const int col = (kbk * 16 + (lane & 15)) ^ ((row & 7) << 3);
        pl[row * 64 + col] = f2bf(p[kbk][j]);
      }
    bf16x8 pf[2];
#pragma unroll
    for (int ks = 0; ks < 2; ++ks) {
      const int row = lane & 15;
      const int col = ((lane >> 4) * 8 + ks * 32) ^ ((row & 7) << 3);
      pf[ks] = *(const bf16x8*)&pl[row * 64 + col];
    }

    // PV: V B-frag from v_t layout (k-contiguous), swizzled read
#pragma unroll
    for (int db = 0; db < 4; ++db) {
#pragma unroll
      for (int ks = 0; ks < 2; ++ks) {
        const int vrow = db * 16 + (lane & 15);
        const int vcol = ((lane >> 4) * 8 + ks * 32) ^ ((vrow & 7) << 3);
        const bf16x8 vf = *(const bf16x8*)&Vlds[vrow * 64 + vcol];
        acc_o[db] = MFMA16(pf[ks], vf, acc_o[db]);
      }
    }
    __syncthreads();
  }

  // epilogue: normalize, Q_len mask, write f32
#pragma unroll
  for (int j = 0; j < 4; ++j) {
    const int row = q0 + w * 16 + (lane >> 4) * 4 + j;
    const float rl = 1.0f / l_run[j];
#pragma unroll
    for (int db = 0; db < 4; ++db) {
      const float v = acc_o[db][j] * rl;
      outb[(size_t)row * 1024 + db * 16 + (lane & 15)] = (row < Lq) ? v : 0.0f;
    }
  }
}

extern "C" void kernel_launch(void* const* d_in, const int* in_sizes, int n_in,
                              void* d_out, int out_size, void* d_ws, size_t ws_size,
                              hipStream_t stream) {
  float* out = (float*)d_out;

  const float* Qs = (const float*)d_in[0];
  const float* Ks = (const float*)d_in[1];
  const float* Vs = (const float*)d_in[2];
  const float* WQ = (const float*)d_in[3];
  const float* WK = (const float*)d_in[4];
  const float* WV = (const float*)d_in[5];
  const int* Qlen = (const int*)d_in[6];
  const int* Vlen = (const int*)d_in[7];

  unsigned short* WQt = (unsigned short*)d_ws;
  unsigned short* WKt = WQt + (size_t)1024 * 1024;
  unsigned short* WVt = WKt + (size_t)1024 * 1024;
  unsigned short* qa  = WVt + (size_t)1024 * 1024;
  unsigned short* ka  = qa + (size_t)8192 * 1024;
  unsigned short* va  = ka + (size_t)8192 * 1024;

  wtrans_kernel<<<dim3(16, 16, 3), 256, 0, stream>>>(WQ, WK, WV, WQt, WKt, WVt);
  proj_gemm_kernel<<<dim3(64, 8, 3), 256, 0, stream>>>(
      Qs, Ks, Vs, WQt, WKt, WVt, qa, ka, va);
  attn_kernel<<<dim3(32, 64), 256, 0, stream>>>(qa, ka, va, Qlen, Vlen, out);
}

// Round 8
// 170.878 us; speedup vs baseline: 1.5881x; 1.0945x over previous
//
#include <hip/hip_runtime.h>
#include <stdint.h>

typedef __attribute__((ext_vector_type(4))) float f32x4;
typedef __attribute__((ext_vector_type(8))) short bf16x8;
typedef __attribute__((ext_vector_type(4))) unsigned short u16x4;

#define MFMA16(a, b, c) __builtin_amdgcn_mfma_f32_16x16x32_bf16((a), (b), (c), 0, 0, 0)

static __device__ __forceinline__ unsigned short f2bf(float x) {
  union { float f; unsigned int u; } v; v.f = x;
  unsigned int r = v.u + 0x7fffu + ((v.u >> 16) & 1u);   // RNE
  return (unsigned short)(r >> 16);
}

static __device__ __forceinline__ void gload_lds16(const void* g, void* l) {
  __builtin_amdgcn_global_load_lds(
      (__attribute__((address_space(1))) void*)(g),
      (__attribute__((address_space(3))) void*)(l), 16, 0, 0);
}

// ---------------- f32 -> bf16 streaming convert (16 elems/thread) ----------------
__global__ __launch_bounds__(256) void conv_kernel(
    const float* __restrict__ in, unsigned short* __restrict__ outp)
{
  const size_t base = ((size_t)blockIdx.x * 256 + threadIdx.x) * 16;
  const f32x4 a0 = *(const f32x4*)&in[base];
  const f32x4 a1 = *(const f32x4*)&in[base + 4];
  const f32x4 a2 = *(const f32x4*)&in[base + 8];
  const f32x4 a3 = *(const f32x4*)&in[base + 12];
  bf16x8 p0, p1;
#pragma unroll
  for (int u = 0; u < 4; ++u) {
    p0[u]     = (short)f2bf(a0[u]);
    p0[u + 4] = (short)f2bf(a1[u]);
    p1[u]     = (short)f2bf(a2[u]);
    p1[u + 4] = (short)f2bf(a3[u]);
  }
  *(bf16x8*)&outp[base]     = p0;
  *(bf16x8*)&outp[base + 8] = p1;
}

// ---------------- weight convert + transpose: Wt[n][k] = bf16(W[k][n]) ----------------
__global__ __launch_bounds__(256) void wtrans_kernel(
    const float* __restrict__ W0, const float* __restrict__ W1, const float* __restrict__ W2,
    unsigned short* __restrict__ T0, unsigned short* __restrict__ T1, unsigned short* __restrict__ T2)
{
  __shared__ __align__(16) float tile[64][65];
  const float* W = (blockIdx.z == 0) ? W0 : (blockIdx.z == 1) ? W1 : W2;
  unsigned short* T = (blockIdx.z == 0) ? T0 : (blockIdx.z == 1) ? T1 : T2;
  const int t = threadIdx.x;
  const int kb = blockIdx.x * 64, nb = blockIdx.y * 64;
  const int rr = t >> 4, cc = (t & 15) * 4;
#pragma unroll
  for (int p = 0; p < 4; ++p) {
    const int r = rr + p * 16;
    const f32x4 v = *(const f32x4*)&W[(size_t)(kb + r) * 1024 + nb + cc];
#pragma unroll
    for (int j = 0; j < 4; ++j) tile[r][cc + j] = v[j];
  }
  __syncthreads();
#pragma unroll
  for (int p = 0; p < 4; ++p) {
    const int n = rr + p * 16;
    u16x4 o;
#pragma unroll
    for (int j = 0; j < 4; ++j) o[j] = f2bf(tile[cc + j][n]);
    *(u16x4*)&T[(size_t)(nb + n) * 1024 + kb + cc] = o;
  }
}

// ---------------- projection GEMM, m97-replica (all-bf16, gload_lds both operands) ----
// C[m][n] = sum_k Ab[m][k] * Wt[n][k];  Ab: bf16 [8192][1024], Wt: bf16 [1024][1024].
// Grid (x=m-tile 64, y=n-tile 8, z): bid%8 = m-tile%8 -> A-panel XCD locality.
// LDS chunk-XOR swizzle via pre-swizzled global source (rule 21), conflict-free (r7: 0).
// logical z (blockIdx.z+zbase): 0 -> qa [bh][s][d] scaled 1/8; 1 -> ka; 2 -> va [bh][d][s].
__global__ __launch_bounds__(256) void proj_gemm_kernel(
    const unsigned short* __restrict__ A0, const unsigned short* __restrict__ A1,
    const unsigned short* __restrict__ A2,
    const unsigned short* __restrict__ B0, const unsigned short* __restrict__ B1,
    const unsigned short* __restrict__ B2,
    unsigned short* __restrict__ O0, unsigned short* __restrict__ O1,
    unsigned short* __restrict__ O2, int zbase)
{
  const int z = blockIdx.z + zbase;
  const unsigned short* Ab = (z == 0) ? A0 : (z == 1) ? A1 : A2;
  const unsigned short* Bt = (z == 0) ? B0 : (z == 1) ? B1 : B2;
  unsigned short* outp = (z == 0) ? O0 : (z == 1) ? O1 : O2;
  const float scale = (z == 0) ? 0.125f : 1.0f;

  __shared__ __align__(16) unsigned short Alds[128 * 32];
  __shared__ __align__(16) unsigned short Blds[128 * 32];
  const int t = threadIdx.x;
  const int lane = t & 63, w = t >> 6;
  const int wr = w >> 1, wc = w & 1;
  const int m0 = blockIdx.x * 128, n0 = blockIdx.y * 128;

  f32x4 acc[4][4] = {};

  for (int kt = 0; kt < 1024; kt += 32) {
    // stage A and B: gload_lds linear dest, pre-swizzled global source chunk
#pragma unroll
    for (int i = 0; i < 2; ++i) {
      const int L = t + i * 256;           // linear chunk index 0..511
      const int r = L >> 2, cs = L & 3;
      const int c = cs ^ ((r >> 1) & 3);
      gload_lds16(&Ab[(size_t)(m0 + r) * 1024 + kt + c * 8], &Alds[L * 8]);
      gload_lds16(&Bt[(size_t)(n0 + r) * 1024 + kt + c * 8], &Blds[L * 8]);
    }
    __syncthreads();

    bf16x8 af[4], bfv[4];
    const int q = lane >> 4;
#pragma unroll
    for (int m = 0; m < 4; ++m) {
      const int row = wr * 64 + m * 16 + (lane & 15);
      af[m] = *(const bf16x8*)&Alds[row * 32 + ((q ^ ((row >> 1) & 3)) * 8)];
    }
#pragma unroll
    for (int n = 0; n < 4; ++n) {
      const int row = wc * 64 + n * 16 + (lane & 15);
      bfv[n] = *(const bf16x8*)&Blds[row * 32 + ((q ^ ((row >> 1) & 3)) * 8)];
    }
#pragma unroll
    for (int m = 0; m < 4; ++m)
#pragma unroll
      for (int n = 0; n < 4; ++n)
        acc[m][n] = MFMA16(af[m], bfv[n], acc[m][n]);
    __syncthreads();
  }

  // epilogue: C/D layout col=lane&15, row=(lane>>4)*4+reg  [m89]
#pragma unroll
  for (int mi = 0; mi < 4; ++mi) {
#pragma unroll
    for (int ni = 0; ni < 4; ++ni) {
      const int nn = n0 + wc * 64 + ni * 16 + (lane & 15);
      const int h = nn >> 6, d = nn & 63;
      const int mbase = m0 + wr * 64 + mi * 16 + ((lane >> 4) << 2);
      const int b = mbase >> 11;
      const int s = mbase & 2047;
      if (z != 2) {
#pragma unroll
        for (int j = 0; j < 4; ++j)
          outp[((size_t)(b * 16 + h) * 2048 + (s + j)) * 64 + d] = f2bf(acc[mi][ni][j] * scale);
      } else {
        u16x4 o;
#pragma unroll
        for (int j = 0; j < 4; ++j) o[j] = f2bf(acc[mi][ni][j]);
        *(u16x4*)&outp[((size_t)(b * 16 + h) * 64 + d) * 2048 + s] = o;
      }
    }
  }
}

// ---------------- flash attention: double-buffered K/V, one barrier per tile ----------
// qa/ka: bf16 [BH][2048][64] (q pre-scaled by 1/8). va: bf16 [BH][64][2048].
// out: f32 [B][2048][1024]. One block = one (b,h) x 64 q-rows; 4 waves x 16 rows.
__global__ __launch_bounds__(256) void attn_kernel(
    const unsigned short* __restrict__ qa, const unsigned short* __restrict__ ka,
    const unsigned short* __restrict__ va, const int* __restrict__ Qlen,
    const int* __restrict__ Vlen, float* __restrict__ outp)
{
  __shared__ __align__(16) unsigned short Klds[2][64 * 64];  // [kpos][d], XOR-swizzled
  __shared__ __align__(16) unsigned short Vlds[2][64 * 64];  // [d][kpos], XOR-swizzled
  __shared__ __align__(16) unsigned short Plds[4][16 * 64];
  const int t = threadIdx.x, lane = t & 63, w = t >> 6;
  const int bh = blockIdx.y, b = bh >> 4, h = bh & 15;
  const int q0 = blockIdx.x * 64;
  const int Lq = Qlen[b], Lv = Vlen[b];
  float* outb = outp + (size_t)b * 2048 * 1024 + h * 64;

  if (q0 >= Lq) {  // entire q-tile masked: zero our 64x64 f32 slab
    const int r = t >> 2, c0 = (t & 3) * 16;
    const f32x4 z = {0.f, 0.f, 0.f, 0.f};
#pragma unroll
    for (int j = 0; j < 4; ++j)
      *(f32x4*)&outb[(size_t)(q0 + r) * 1024 + c0 + j * 4] = z;
    return;
  }

  const unsigned short* qb = qa + (size_t)bh * 2048 * 64;
  const unsigned short* kb = ka + (size_t)bh * 2048 * 64;
  const unsigned short* vb = va + (size_t)bh * 64 * 2048;

  // per-thread staging geometry (512 chunks of 8 elems per 64x64 tile)
  const int sr0 = t >> 3, sc0 = t & 7;                 // chunk i=0
  const int sr1 = (t + 256) >> 3, sc1 = (t + 256) & 7; // chunk i=1
  const int sd0 = sr0 * 64 + ((sc0 ^ (sr0 & 7)) * 8);
  const int sd1 = sr1 * 64 + ((sc1 ^ (sr1 & 7)) * 8);

  bf16x8 aq[2];
  {
    const int qrow = q0 + w * 16 + (lane & 15);
#pragma unroll
    for (int f = 0; f < 2; ++f)
      aq[f] = *(const bf16x8*)&qb[(size_t)qrow * 64 + (lane >> 4) * 8 + f * 32];
  }

  float m_run[4], l_run[4];
  f32x4 acc_o[4] = {};
#pragma unroll
  for (int j = 0; j < 4; ++j) { m_run[j] = -3.0e38f; l_run[j] = 0.0f; }

  const int nt = (Lv + 63) >> 6;

  // prologue: tile 0 -> regs -> buf 0
  bf16x8 kr0 = *(const bf16x8*)&kb[(size_t)sr0 * 64 + sc0 * 8];
  bf16x8 kr1 = *(const bf16x8*)&kb[(size_t)sr1 * 64 + sc1 * 8];
  bf16x8 vr0 = *(const bf16x8*)&vb[(size_t)sr0 * 2048 + sc0 * 8];
  bf16x8 vr1 = *(const bf16x8*)&vb[(size_t)sr1 * 2048 + sc1 * 8];
  *(bf16x8*)&Klds[0][sd0] = kr0;  *(bf16x8*)&Klds[0][sd1] = kr1;
  *(bf16x8*)&Vlds[0][sd0] = vr0;  *(bf16x8*)&Vlds[0][sd1] = vr1;

  for (int kt = 0; kt < nt; ++kt) {
    __syncthreads();                       // buf[kt&1] visible to all waves
    const int cur = kt & 1;
    const unsigned short* Kc = &Klds[cur][0];
    const unsigned short* Vc = &Vlds[cur][0];
    const int k0 = kt * 64;

    // prefetch tile kt+1 into regs (HBM latency hides under compute below)
    const bool more = (kt + 1) < nt;
    if (more) {
      const int kn = k0 + 64;
      kr0 = *(const bf16x8*)&kb[(size_t)(kn + sr0) * 64 + sc0 * 8];
      kr1 = *(const bf16x8*)&kb[(size_t)(kn + sr1) * 64 + sc1 * 8];
      vr0 = *(const bf16x8*)&vb[(size_t)sr0 * 2048 + kn + sc0 * 8];
      vr1 = *(const bf16x8*)&vb[(size_t)sr1 * 2048 + kn + sc1 * 8];
    }

    // QK^T: S-tile 16q x 64k per wave; B-frag rows = kpos, swizzled read
    f32x4 s4[4];
#pragma unroll
    for (int kbk = 0; kbk < 4; ++kbk) {
      const int row = kbk * 16 + (lane & 15);
      f32x4 acc = {0.f, 0.f, 0.f, 0.f};
#pragma unroll
      for (int ds = 0; ds < 2; ++ds) {
        const int col = (((lane >> 4) * 8) + ds * 32) ^ ((row & 7) << 3);
        const bf16x8 bk = *(const bf16x8*)&Kc[row * 64 + col];
        acc = MFMA16(aq[ds], bk, acc);
      }
      if (k0 + row >= Lv) {
#pragma unroll
        for (int j = 0; j < 4; ++j) acc[j] = -1e30f;
      }
      s4[kbk] = acc;
    }

    // online softmax
    f32x4 rm;
#pragma unroll
    for (int j = 0; j < 4; ++j)
      rm[j] = fmaxf(fmaxf(s4[0][j], s4[1][j]), fmaxf(s4[2][j], s4[3][j]));
#pragma unroll
    for (int msk = 1; msk <= 8; msk <<= 1)
#pragma unroll
      for (int j = 0; j < 4; ++j)
        rm[j] = fmaxf(rm[j], __shfl_xor(rm[j], msk));

    float mn[4], esc[4];
#pragma unroll
    for (int j = 0; j < 4; ++j) {
      mn[j] = fmaxf(m_run[j], rm[j]);
      esc[j] = __expf(m_run[j] - mn[j]);
      m_run[j] = mn[j];
    }

    float p[4][4];
    f32x4 rs = {0.f, 0.f, 0.f, 0.f};
#pragma unroll
    for (int kbk = 0; kbk < 4; ++kbk)
#pragma unroll
      for (int j = 0; j < 4; ++j) {
        p[kbk][j] = __expf(s4[kbk][j] - mn[j]);
        rs[j] += p[kbk][j];
      }
#pragma unroll
    for (int msk = 1; msk <= 8; msk <<= 1)
#pragma unroll
      for (int j = 0; j < 4; ++j)
        rs[j] += __shfl_xor(rs[j], msk);
#pragma unroll
    for (int j = 0; j < 4; ++j) l_run[j] = l_run[j] * esc[j] + rs[j];
#pragma unroll
    for (int d = 0; d < 4; ++d)
#pragma unroll
      for (int j = 0; j < 4; ++j) acc_o[d][j] *= esc[j];

    // P (C-layout) -> per-wave LDS (swizzled) -> A-fragments
    unsigned short* pl = &Plds[w][0];
#pragma unroll
    for (int kbk = 0; kbk < 4; ++kbk)
#pragma unroll
      for (int j = 0; j < 4; ++j) {
        const int row = (lane >> 4) * 4 + j;
        const int col = (kbk * 16 + (lane & 15)) ^ ((row & 7) << 3);
        pl[row * 64 + col] = f2bf(p[kbk][j]);
      }
    bf16x8 pf[2];
#pragma unroll
    for (int ks = 0; ks < 2; ++ks) {
      const int row = lane & 15;
      const int col = ((lane >> 4) * 8 + ks * 32) ^ ((row & 7) << 3);
      pf[ks] = *(const bf16x8*)&pl[row * 64 + col];
    }

    // PV: V B-frag from v_t layout (k-contiguous), swizzled read
#pragma unroll
    for (int db = 0; db < 4; ++db) {
#pragma unroll
      for (int ks = 0; ks < 2; ++ks) {
        const int vrow = db * 16 + (lane & 15);
        const int vcol = ((lane >> 4) * 8 + ks * 32) ^ ((vrow & 7) << 3);
        const bf16x8 vf = *(const bf16x8*)&Vc[vrow * 64 + vcol];
        acc_o[db] = MFMA16(pf[ks], vf, acc_o[db]);
      }
    }

    // write prefetched tile into the other buffer (no race: readers use buf[cur])
    if (more) {
      unsigned short* Kn = &Klds[cur ^ 1][0];
      unsigned short* Vn = &Vlds[cur ^ 1][0];
      *(bf16x8*)&Kn[sd0] = kr0;  *(bf16x8*)&Kn[sd1] = kr1;
      *(bf16x8*)&Vn[sd0] = vr0;  *(bf16x8*)&Vn[sd1] = vr1;
    }
  }

  // epilogue: normalize, Q_len mask, write f32
#pragma unroll
  for (int j = 0; j < 4; ++j) {
    const int row = q0 + w * 16 + (lane >> 4) * 4 + j;
    const float rl = 1.0f / l_run[j];
#pragma unroll
    for (int db = 0; db < 4; ++db) {
      const float v = acc_o[db][j] * rl;
      outb[(size_t)row * 1024 + db * 16 + (lane & 15)] = (row < Lq) ? v : 0.0f;
    }
  }
}

extern "C" void kernel_launch(void* const* d_in, const int* in_sizes, int n_in,
                              void* d_out, int out_size, void* d_ws, size_t ws_size,
                              hipStream_t stream) {
  float* out = (float*)d_out;

  const float* Qs = (const float*)d_in[0];
  const float* Ks = (const float*)d_in[1];
  const float* Vs = (const float*)d_in[2];
  const float* WQ = (const float*)d_in[3];
  const float* WK = (const float*)d_in[4];
  const float* WV = (const float*)d_in[5];
  const int* Qlen = (const int*)d_in[6];
  const int* Vlen = (const int*)d_in[7];

  unsigned short* WQt = (unsigned short*)d_ws;
  unsigned short* WKt = WQt + (size_t)1024 * 1024;
  unsigned short* WVt = WKt + (size_t)1024 * 1024;
  unsigned short* qa  = WVt + (size_t)1024 * 1024;
  unsigned short* ka  = qa + (size_t)8192 * 1024;
  unsigned short* va  = ka + (size_t)8192 * 1024;
  unsigned short* ext = va + (size_t)8192 * 1024;   // optional 3rd A-buffer

  // converted-A buffers: d_out used as scratch (attn rewrites it fully at the end)
  unsigned short* cA = (unsigned short*)d_out;              // 8M bf16 = 16 MB
  unsigned short* cB = cA + (size_t)8192 * 1024;            // second 16 MB

  const size_t base_need = ((size_t)3 * 1024 * 1024 + (size_t)3 * 8192 * 1024) * 2;
  const size_t ext_need  = base_need + (size_t)8192 * 1024 * 2;

  wtrans_kernel<<<dim3(16, 16, 3), 256, 0, stream>>>(WQ, WK, WV, WQt, WKt, WVt);
  conv_kernel<<<2048, 256, 0, stream>>>(Qs, cA);
  conv_kernel<<<2048, 256, 0, stream>>>(Ks, cB);

  if (ws_size >= ext_need) {
    conv_kernel<<<2048, 256, 0, stream>>>(Vs, ext);
    proj_gemm_kernel<<<dim3(64, 8, 3), 256, 0, stream>>>(
        cA, cB, ext, WQt, WKt, WVt, qa, ka, va, 0);
  } else {
    proj_gemm_kernel<<<dim3(64, 8, 2), 256, 0, stream>>>(
        cA, cB, cB, WQt, WKt, WVt, qa, ka, va, 0);
    conv_kernel<<<2048, 256, 0, stream>>>(Vs, cA);
    proj_gemm_kernel<<<dim3(64, 8, 1), 256, 0, stream>>>(
        cA, cA, cA, WQt, WKt, WVt, qa, ka, va, 2);
  }
  attn_kernel<<<dim3(32, 64), 256, 0, stream>>>(qa, ka, va, Qlen, Vlen, out);
}

// Round 9
// 159.113 us; speedup vs baseline: 1.7055x; 1.0739x over previous
//
#include <hip/hip_runtime.h>
#include <stdint.h>

typedef __attribute__((ext_vector_type(4))) float f32x4;
typedef __attribute__((ext_vector_type(8))) short bf16x8;
typedef __attribute__((ext_vector_type(4))) unsigned short u16x4;

#define MFMA16(a, b, c) __builtin_amdgcn_mfma_f32_16x16x32_bf16((a), (b), (c), 0, 0, 0)

static __device__ __forceinline__ unsigned short f2bf(float x) {
  union { float f; unsigned int u; } v; v.f = x;
  unsigned int r = v.u + 0x7fffu + ((v.u >> 16) & 1u);   // RNE
  return (unsigned short)(r >> 16);
}

static __device__ __forceinline__ void gload_lds16(const void* g, void* l) {
  __builtin_amdgcn_global_load_lds(
      (__attribute__((address_space(1))) void*)(g),
      (__attribute__((address_space(3))) void*)(l), 16, 0, 0);
}

// DPP lane-permute on the VALU pipe (no LDS-pipe traffic, ~4cyc vs ~120cyc shuffle)
template <int CTRL>
static __device__ __forceinline__ float dpp_mov(float x) {
  union { float f; int i; } u, r;
  u.f = x;
  r.i = __builtin_amdgcn_update_dpp(u.i, u.i, CTRL, 0xF, 0xF, false);
  return r.f;
}
// 16-lane reduce: {^1},{^2},{rot4},{rot8} covers all 16 lanes of each row
static __device__ __forceinline__ float dpp_max16(float x) {
  x = fmaxf(x, dpp_mov<0xB1>(x));    // quad_perm [1,0,3,2]
  x = fmaxf(x, dpp_mov<0x4E>(x));    // quad_perm [2,3,0,1]
  x = fmaxf(x, dpp_mov<0x124>(x));   // row_ror:4
  x = fmaxf(x, dpp_mov<0x128>(x));   // row_ror:8
  return x;
}
static __device__ __forceinline__ float dpp_sum16(float x) {
  x += dpp_mov<0xB1>(x);
  x += dpp_mov<0x4E>(x);
  x += dpp_mov<0x124>(x);
  x += dpp_mov<0x128>(x);
  return x;
}

// ---------------- f32 -> bf16 streaming convert, 3 tensors in one dispatch ----------
__global__ __launch_bounds__(256) void conv3_kernel(
    const float* __restrict__ S0, const float* __restrict__ S1, const float* __restrict__ S2,
    unsigned short* __restrict__ D0, unsigned short* __restrict__ D1,
    unsigned short* __restrict__ D2)
{
  const float* in = (blockIdx.y == 0) ? S0 : (blockIdx.y == 1) ? S1 : S2;
  unsigned short* outp = (blockIdx.y == 0) ? D0 : (blockIdx.y == 1) ? D1 : D2;
  const size_t base = ((size_t)blockIdx.x * 256 + threadIdx.x) * 16;
  const f32x4 a0 = *(const f32x4*)&in[base];
  const f32x4 a1 = *(const f32x4*)&in[base + 4];
  const f32x4 a2 = *(const f32x4*)&in[base + 8];
  const f32x4 a3 = *(const f32x4*)&in[base + 12];
  bf16x8 p0, p1;
#pragma unroll
  for (int u = 0; u < 4; ++u) {
    p0[u]     = (short)f2bf(a0[u]);
    p0[u + 4] = (short)f2bf(a1[u]);
    p1[u]     = (short)f2bf(a2[u]);
    p1[u + 4] = (short)f2bf(a3[u]);
  }
  *(bf16x8*)&outp[base]     = p0;
  *(bf16x8*)&outp[base + 8] = p1;
}

__global__ __launch_bounds__(256) void conv_kernel(
    const float* __restrict__ in, unsigned short* __restrict__ outp)
{
  const size_t base = ((size_t)blockIdx.x * 256 + threadIdx.x) * 16;
  const f32x4 a0 = *(const f32x4*)&in[base];
  const f32x4 a1 = *(const f32x4*)&in[base + 4];
  const f32x4 a2 = *(const f32x4*)&in[base + 8];
  const f32x4 a3 = *(const f32x4*)&in[base + 12];
  bf16x8 p0, p1;
#pragma unroll
  for (int u = 0; u < 4; ++u) {
    p0[u]     = (short)f2bf(a0[u]);
    p0[u + 4] = (short)f2bf(a1[u]);
    p1[u]     = (short)f2bf(a2[u]);
    p1[u + 4] = (short)f2bf(a3[u]);
  }
  *(bf16x8*)&outp[base]     = p0;
  *(bf16x8*)&outp[base + 8] = p1;
}

// ---------------- weight convert + transpose: Wt[n][k] = bf16(W[k][n]) ----------------
__global__ __launch_bounds__(256) void wtrans_kernel(
    const float* __restrict__ W0, const float* __restrict__ W1, const float* __restrict__ W2,
    unsigned short* __restrict__ T0, unsigned short* __restrict__ T1, unsigned short* __restrict__ T2)
{
  __shared__ __align__(16) float tile[64][65];
  const float* W = (blockIdx.z == 0) ? W0 : (blockIdx.z == 1) ? W1 : W2;
  unsigned short* T = (blockIdx.z == 0) ? T0 : (blockIdx.z == 1) ? T1 : T2;
  const int t = threadIdx.x;
  const int kb = blockIdx.x * 64, nb = blockIdx.y * 64;
  const int rr = t >> 4, cc = (t & 15) * 4;
#pragma unroll
  for (int p = 0; p < 4; ++p) {
    const int r = rr + p * 16;
    const f32x4 v = *(const f32x4*)&W[(size_t)(kb + r) * 1024 + nb + cc];
#pragma unroll
    for (int j = 0; j < 4; ++j) tile[r][cc + j] = v[j];
  }
  __syncthreads();
#pragma unroll
  for (int p = 0; p < 4; ++p) {
    const int n = rr + p * 16;
    u16x4 o;
#pragma unroll
    for (int j = 0; j < 4; ++j) o[j] = f2bf(tile[cc + j][n]);
    *(u16x4*)&T[(size_t)(nb + n) * 1024 + kb + cc] = o;
  }
}

// ---------------- projection GEMM, m97-replica (all-bf16, gload_lds both operands) ----
__global__ __launch_bounds__(256) void proj_gemm_kernel(
    const unsigned short* __restrict__ A0, const unsigned short* __restrict__ A1,
    const unsigned short* __restrict__ A2,
    const unsigned short* __restrict__ B0, const unsigned short* __restrict__ B1,
    const unsigned short* __restrict__ B2,
    unsigned short* __restrict__ O0, unsigned short* __restrict__ O1,
    unsigned short* __restrict__ O2, int zbase)
{
  const int z = blockIdx.z + zbase;
  const unsigned short* Ab = (z == 0) ? A0 : (z == 1) ? A1 : A2;
  const unsigned short* Bt = (z == 0) ? B0 : (z == 1) ? B1 : B2;
  unsigned short* outp = (z == 0) ? O0 : (z == 1) ? O1 : O2;
  const float scale = (z == 0) ? 0.125f : 1.0f;

  __shared__ __align__(16) unsigned short Alds[128 * 32];
  __shared__ __align__(16) unsigned short Blds[128 * 32];
  const int t = threadIdx.x;
  const int lane = t & 63, w = t >> 6;
  const int wr = w >> 1, wc = w & 1;
  const int m0 = blockIdx.x * 128, n0 = blockIdx.y * 128;

  f32x4 acc[4][4] = {};

  for (int kt = 0; kt < 1024; kt += 32) {
#pragma unroll
    for (int i = 0; i < 2; ++i) {
      const int L = t + i * 256;           // linear chunk index 0..511
      const int r = L >> 2, cs = L & 3;
      const int c = cs ^ ((r >> 1) & 3);
      gload_lds16(&Ab[(size_t)(m0 + r) * 1024 + kt + c * 8], &Alds[L * 8]);
      gload_lds16(&Bt[(size_t)(n0 + r) * 1024 + kt + c * 8], &Blds[L * 8]);
    }
    __syncthreads();

    bf16x8 af[4], bfv[4];
    const int q = lane >> 4;
#pragma unroll
    for (int m = 0; m < 4; ++m) {
      const int row = wr * 64 + m * 16 + (lane & 15);
      af[m] = *(const bf16x8*)&Alds[row * 32 + ((q ^ ((row >> 1) & 3)) * 8)];
    }
#pragma unroll
    for (int n = 0; n < 4; ++n) {
      const int row = wc * 64 + n * 16 + (lane & 15);
      bfv[n] = *(const bf16x8*)&Blds[row * 32 + ((q ^ ((row >> 1) & 3)) * 8)];
    }
#pragma unroll
    for (int m = 0; m < 4; ++m)
#pragma unroll
      for (int n = 0; n < 4; ++n)
        acc[m][n] = MFMA16(af[m], bfv[n], acc[m][n]);
    __syncthreads();
  }

#pragma unroll
  for (int mi = 0; mi < 4; ++mi) {
#pragma unroll
    for (int ni = 0; ni < 4; ++ni) {
      const int nn = n0 + wc * 64 + ni * 16 + (lane & 15);
      const int h = nn >> 6, d = nn & 63;
      const int mbase = m0 + wr * 64 + mi * 16 + ((lane >> 4) << 2);
      const int b = mbase >> 11;
      const int s = mbase & 2047;
      if (z != 2) {
#pragma unroll
        for (int j = 0; j < 4; ++j)
          outp[((size_t)(b * 16 + h) * 2048 + (s + j)) * 64 + d] = f2bf(acc[mi][ni][j] * scale);
      } else {
        u16x4 o;
#pragma unroll
        for (int j = 0; j < 4; ++j) o[j] = f2bf(acc[mi][ni][j]);
        *(u16x4*)&outp[((size_t)(b * 16 + h) * 64 + d) * 2048 + s] = o;
      }
    }
  }
}

// ---------------- flash attention: dbuf K/V, DPP softmax reduce ----------
// qa/ka: bf16 [BH][2048][64] (q pre-scaled by 1/8). va: bf16 [BH][64][2048].
// out: f32 [B][2048][1024]. One block = one (b,h) x 64 q-rows; 4 waves x 16 rows.
__global__ __launch_bounds__(256) void attn_kernel(
    const unsigned short* __restrict__ qa, const unsigned short* __restrict__ ka,
    const unsigned short* __restrict__ va, const int* __restrict__ Qlen,
    const int* __restrict__ Vlen, float* __restrict__ outp)
{
  __shared__ __align__(16) unsigned short Klds[2][64 * 64];  // [kpos][d], XOR-swizzled
  __shared__ __align__(16) unsigned short Vlds[2][64 * 64];  // [d][kpos], XOR-swizzled
  __shared__ __align__(16) unsigned short Plds[4][16 * 64];
  const int t = threadIdx.x, lane = t & 63, w = t >> 6;
  const int bh = blockIdx.y, b = bh >> 4, h = bh & 15;
  const int q0 = blockIdx.x * 64;
  const int Lq = Qlen[b], Lv = Vlen[b];
  float* outb = outp + (size_t)b * 2048 * 1024 + h * 64;

  if (q0 >= Lq) {  // entire q-tile masked: zero our 64x64 f32 slab
    const int r = t >> 2, c0 = (t & 3) * 16;
    const f32x4 z = {0.f, 0.f, 0.f, 0.f};
#pragma unroll
    for (int j = 0; j < 4; ++j)
      *(f32x4*)&outb[(size_t)(q0 + r) * 1024 + c0 + j * 4] = z;
    return;
  }

  const unsigned short* qb = qa + (size_t)bh * 2048 * 64;
  const unsigned short* kb = ka + (size_t)bh * 2048 * 64;
  const unsigned short* vb = va + (size_t)bh * 64 * 2048;

  // per-thread staging geometry (512 chunks of 8 elems per 64x64 tile)
  const int sr0 = t >> 3, sc0 = t & 7;                 // chunk i=0
  const int sr1 = (t + 256) >> 3, sc1 = (t + 256) & 7; // chunk i=1
  const int sd0 = sr0 * 64 + ((sc0 ^ (sr0 & 7)) * 8);
  const int sd1 = sr1 * 64 + ((sc1 ^ (sr1 & 7)) * 8);

  bf16x8 aq[2];
  {
    const int qrow = q0 + w * 16 + (lane & 15);
#pragma unroll
    for (int f = 0; f < 2; ++f)
      aq[f] = *(const bf16x8*)&qb[(size_t)qrow * 64 + (lane >> 4) * 8 + f * 32];
  }

  float m_run[4], l_run[4];
  f32x4 acc_o[4] = {};
#pragma unroll
  for (int j = 0; j < 4; ++j) { m_run[j] = -3.0e38f; l_run[j] = 0.0f; }

  const int nt = (Lv + 63) >> 6;

  // prologue: tile 0 -> regs -> buf 0
  bf16x8 kr0 = *(const bf16x8*)&kb[(size_t)sr0 * 64 + sc0 * 8];
  bf16x8 kr1 = *(const bf16x8*)&kb[(size_t)sr1 * 64 + sc1 * 8];
  bf16x8 vr0 = *(const bf16x8*)&vb[(size_t)sr0 * 2048 + sc0 * 8];
  bf16x8 vr1 = *(const bf16x8*)&vb[(size_t)sr1 * 2048 + sc1 * 8];
  *(bf16x8*)&Klds[0][sd0] = kr0;  *(bf16x8*)&Klds[0][sd1] = kr1;
  *(bf16x8*)&Vlds[0][sd0] = vr0;  *(bf16x8*)&Vlds[0][sd1] = vr1;

  for (int kt = 0; kt < nt; ++kt) {
    __syncthreads();                       // buf[kt&1] visible to all waves
    const int cur = kt & 1;
    const unsigned short* Kc = &Klds[cur][0];
    const unsigned short* Vc = &Vlds[cur][0];
    const int k0 = kt * 64;

    // prefetch tile kt+1 into regs (HBM latency hides under compute below)
    const bool more = (kt + 1) < nt;
    if (more) {
      const int kn = k0 + 64;
      kr0 = *(const bf16x8*)&kb[(size_t)(kn + sr0) * 64 + sc0 * 8];
      kr1 = *(const bf16x8*)&kb[(size_t)(kn + sr1) * 64 + sc1 * 8];
      vr0 = *(const bf16x8*)&vb[(size_t)sr0 * 2048 + kn + sc0 * 8];
      vr1 = *(const bf16x8*)&vb[(size_t)sr1 * 2048 + kn + sc1 * 8];
    }

    // QK^T: S-tile 16q x 64k per wave; B-frag rows = kpos, swizzled read
    f32x4 s4[4];
#pragma unroll
    for (int kbk = 0; kbk < 4; ++kbk) {
      const int row = kbk * 16 + (lane & 15);
      f32x4 acc = {0.f, 0.f, 0.f, 0.f};
#pragma unroll
      for (int ds = 0; ds < 2; ++ds) {
        const int col = (((lane >> 4) * 8) + ds * 32) ^ ((row & 7) << 3);
        const bf16x8 bk = *(const bf16x8*)&Kc[row * 64 + col];
        acc = MFMA16(aq[ds], bk, acc);
      }
      if (k0 + row >= Lv) {
#pragma unroll
        for (int j = 0; j < 4; ++j) acc[j] = -1e30f;
      }
      s4[kbk] = acc;
    }

    // online softmax: rowmax via DPP (VALU pipe, no LDS-pipe latency)
    float mn[4], esc[4];
#pragma unroll
    for (int j = 0; j < 4; ++j) {
      float rm = fmaxf(fmaxf(s4[0][j], s4[1][j]), fmaxf(s4[2][j], s4[3][j]));
      rm = dpp_max16(rm);
      mn[j] = fmaxf(m_run[j], rm);
      esc[j] = __expf(m_run[j] - mn[j]);
      m_run[j] = mn[j];
    }

    // exp + local sum
    float p[4][4];
    float rs[4] = {0.f, 0.f, 0.f, 0.f};
#pragma unroll
    for (int kbk = 0; kbk < 4; ++kbk)
#pragma unroll
      for (int j = 0; j < 4; ++j) {
        p[kbk][j] = __expf(s4[kbk][j] - mn[j]);
        rs[j] += p[kbk][j];
      }

    // write P to LDS FIRST (its latency hides under the DPP reduce + rescale below)
    unsigned short* pl = &Plds[w][0];
#pragma unroll
    for (int kbk = 0; kbk < 4; ++kbk)
#pragma unroll
      for (int j = 0; j < 4; ++j) {
        const int row = (lane >> 4) * 4 + j;
        const int col = (kbk * 16 + (lane & 15)) ^ ((row & 7) << 3);
        pl[row * 64 + col] = f2bf(p[kbk][j]);
      }

    // sum reduce via DPP + state update + rescale (overlaps P-write latency)
#pragma unroll
    for (int j = 0; j < 4; ++j) {
      const float s = dpp_sum16(rs[j]);
      l_run[j] = l_run[j] * esc[j] + s;
    }
#pragma unroll
    for (int d = 0; d < 4; ++d)
#pragma unroll
      for (int j = 0; j < 4; ++j) acc_o[d][j] *= esc[j];

    bf16x8 pf[2];
#pragma unroll
    for (int ks = 0; ks < 2; ++ks) {
      const int row = lane & 15;
      const int col = ((lane >> 4) * 8 + ks * 32) ^ ((row & 7) << 3);
      pf[ks] = *(const bf16x8*)&pl[row * 64 + col];
    }

    // PV: V B-frag from v_t layout (k-contiguous), swizzled read
#pragma unroll
    for (int db = 0; db < 4; ++db) {
#pragma unroll
      for (int ks = 0; ks < 2; ++ks) {
        const int vrow = db * 16 + (lane & 15);
        const int vcol = ((lane >> 4) * 8 + ks * 32) ^ ((vrow & 7) << 3);
        const bf16x8 vf = *(const bf16x8*)&Vc[vrow * 64 + vcol];
        acc_o[db] = MFMA16(pf[ks], vf, acc_o[db]);
      }
    }

    // write prefetched tile into the other buffer (no race: readers use buf[cur])
    if (more) {
      unsigned short* Kn = &Klds[cur ^ 1][0];
      unsigned short* Vn = &Vlds[cur ^ 1][0];
      *(bf16x8*)&Kn[sd0] = kr0;  *(bf16x8*)&Kn[sd1] = kr1;
      *(bf16x8*)&Vn[sd0] = vr0;  *(bf16x8*)&Vn[sd1] = vr1;
    }
  }

  // epilogue: normalize, Q_len mask, write f32
#pragma unroll
  for (int j = 0; j < 4; ++j) {
    const int row = q0 + w * 16 + (lane >> 4) * 4 + j;
    const float rl = 1.0f / l_run[j];
#pragma unroll
    for (int db = 0; db < 4; ++db) {
      const float v = acc_o[db][j] * rl;
      outb[(size_t)row * 1024 + db * 16 + (lane & 15)] = (row < Lq) ? v : 0.0f;
    }
  }
}

extern "C" void kernel_launch(void* const* d_in, const int* in_sizes, int n_in,
                              void* d_out, int out_size, void* d_ws, size_t ws_size,
                              hipStream_t stream) {
  float* out = (float*)d_out;

  const float* Qs = (const float*)d_in[0];
  const float* Ks = (const float*)d_in[1];
  const float* Vs = (const float*)d_in[2];
  const float* WQ = (const float*)d_in[3];
  const float* WK = (const float*)d_in[4];
  const float* WV = (const float*)d_in[5];
  const int* Qlen = (const int*)d_in[6];
  const int* Vlen = (const int*)d_in[7];

  unsigned short* WQt = (unsigned short*)d_ws;
  unsigned short* WKt = WQt + (size_t)1024 * 1024;
  unsigned short* WVt = WKt + (size_t)1024 * 1024;
  unsigned short* qa  = WVt + (size_t)1024 * 1024;
  unsigned short* ka  = qa + (size_t)8192 * 1024;
  unsigned short* va  = ka + (size_t)8192 * 1024;
  unsigned short* ext = va + (size_t)8192 * 1024;   // optional 3rd A-buffer

  // converted-A buffers: d_out used as scratch (attn rewrites it fully at the end)
  unsigned short* cA = (unsigned short*)d_out;              // 8M bf16 = 16 MB
  unsigned short* cB = cA + (size_t)8192 * 1024;            // second 16 MB

  const size_t base_need = ((size_t)3 * 1024 * 1024 + (size_t)3 * 8192 * 1024) * 2;
  const size_t ext_need  = base_need + (size_t)8192 * 1024 * 2;

  wtrans_kernel<<<dim3(16, 16, 3), 256, 0, stream>>>(WQ, WK, WV, WQt, WKt, WVt);

  if (ws_size >= ext_need) {
    conv3_kernel<<<dim3(2048, 3), 256, 0, stream>>>(Qs, Ks, Vs, cA, cB, ext);
    proj_gemm_kernel<<<dim3(64, 8, 3), 256, 0, stream>>>(
        cA, cB, ext, WQt, WKt, WVt, qa, ka, va, 0);
  } else {
    conv_kernel<<<2048, 256, 0, stream>>>(Qs, cA);
    conv_kernel<<<2048, 256, 0, stream>>>(Ks, cB);
    proj_gemm_kernel<<<dim3(64, 8, 2), 256, 0, stream>>>(
        cA, cB, cB, WQt, WKt, WVt, qa, ka, va, 0);
    conv_kernel<<<2048, 256, 0, stream>>>(Vs, cA);
    proj_gemm_kernel<<<dim3(64, 8, 1), 256, 0, stream>>>(
        cA, cA, cA, WQt, WKt, WVt, qa, ka, va, 2);
  }
  attn_kernel<<<dim3(32, 64), 256, 0, stream>>>(qa, ka, va, Qlen, Vlen, out);
}